// Round 12
// baseline (400.620 us; speedup 1.0000x reference)
//
#include <hip/hip_runtime.h>
#include <math.h>

// Problem constants
#define BB 4
#define NN 1000
#define TT 8
#define FF 64
#define HH 64
#define NHEADS 4
#define EE 16000
#define E2 17000          // EE + NN self-loops (EXACT per-graph edge total)
#define GG (BB*TT)        // 32 graphs
#define GN (GG*NN)        // 32000 (graph,node) pairs
#define NROWS (BB*NN)     // 4000 GRU rows

typedef __attribute__((ext_vector_type(8))) short bf16x8;
typedef __attribute__((ext_vector_type(4))) float f32x4;

// ---------------- helpers ----------------
__device__ __forceinline__ float sigmoidf_(float x) {
    return 1.f / (1.f + __expf(-x));
}
__device__ __forceinline__ float tanhf_(float x) {
    x = fminf(fmaxf(x, -15.f), 15.f);
    float e = __expf(2.f * x);
    return (e - 1.f) / (e + 1.f);
}
__device__ __forceinline__ float leaky_(float x) {
    return (x > 0.f) ? x : 0.2f * x;
}
__device__ __forceinline__ ushort bf16_rne(float v) {
    uint b = __float_as_uint(v);
    return (ushort)((b + 0x7FFF + ((b >> 16) & 1)) >> 16);
}

// ---------------- CSR build ----------------
__global__ void count_edges(const int* __restrict__ ei, int* __restrict__ counts) {
    int g = blockIdx.y;
    int e = blockIdx.x * 256 + threadIdx.x;
    if (e >= E2) return;
    int dst;
    if (e < EE) dst = ei[(size_t)g * 2 * EE + EE + e];
    else        dst = e - EE;   // self-loop
    atomicAdd(&counts[g * NN + dst], 1);
}

__global__ __launch_bounds__(256) void scan_offsets_pg(const int* __restrict__ counts,
                                                       int* __restrict__ offs) {
    __shared__ int tot[256];
    int g = blockIdx.x;
    int tid = threadIdx.x;
    int base = tid * 4;
    int c0 = 0, c1 = 0, c2 = 0, c3 = 0;
    if (base < NN) {
        int4 v = *(const int4*)(counts + (size_t)g * NN + base);  // 16B aligned (NN%4==0)
        c0 = v.x; c1 = v.y; c2 = v.z; c3 = v.w;
    }
    int s = c0 + c1 + c2 + c3;
    tot[tid] = s;
    __syncthreads();
    for (int off = 1; off < 256; off <<= 1) {
        int y = (tid >= off) ? tot[tid - off] : 0;
        __syncthreads();
        tot[tid] += y;
        __syncthreads();
    }
    int run = g * E2 + tot[tid] - s;  // exclusive prefix + graph base
    if (base < NN) {
        int4 o;
        o.x = run; run += c0;
        o.y = run; run += c1;
        o.z = run; run += c2;
        o.w = run;
        *(int4*)(offs + (size_t)g * NN + base) = o;
    }
    if (g == 0 && tid == 0) offs[GN] = GG * E2;
}

__global__ void scatter_edges(const int* __restrict__ ei, const int* __restrict__ offs,
                              int* __restrict__ cursor, int* __restrict__ csr) {
    int g = blockIdx.y;
    int e = blockIdx.x * 256 + threadIdx.x;
    if (e >= E2) return;
    int src, dst;
    if (e < EE) {
        src = ei[(size_t)g * 2 * EE + e];
        dst = ei[(size_t)g * 2 * EE + EE + e];
    } else {
        src = dst = e - EE;
    }
    int i = g * NN + dst;
    int pos = offs[i] + atomicAdd(&cursor[i], 1);
    csr[pos] = src;
}

// Register pin (used by gru_gi; kept frozen there)
#define PIN64_(arr)                                        \
    _Pragma("unroll")                                      \
    for (int _pi = 0; _pi < 64; ++_pi)                     \
        asm volatile("" : "+v"((arr)[_pi]));

// ---------------- MFMA GAT linear (R10: LDS-staged coalesced epilogue; FROZEN) ----------------
// Bpack per W: [wq(2)][kb(2)][nt(16)][col(16)][koct(4)][j(8)] bf16 = 64KB
__global__ __launch_bounds__(64) void wprep(
    const float* __restrict__ W1, const float* __restrict__ W2,
    ushort* __restrict__ B1, ushort* __restrict__ B2) {
    int blk = blockIdx.x;                  // 128 blocks
    const float* W = (blk >> 6) ? W2 : W1;
    ushort* Bp = (blk >> 6) ? B2 : B1;
    int r = blk & 63;
    int wq = r >> 5, kb = (r >> 4) & 1, nt = r & 15;
    int tid = threadIdx.x;                 // 64
    int col = tid >> 2, koct = tid & 3;
    int c = nt * 16 + col;
    ushort o[8];
#pragma unroll
    for (int j = 0; j < 8; ++j) {
        int k = kb * 32 + koct * 8 + j;
        float v = W[k * 256 + c];
        ushort h = bf16_rne(v);
        if (wq == 0) o[j] = h;
        else {
            float hf = __uint_as_float(((uint)h) << 16);
            o[j] = bf16_rne(v - hf);
        }
    }
    size_t off = (((size_t)((wq * 2 + kb) * 16 + nt) * 16 + col) * 4 + koct) * 8;
    uint4 ow;
    ow.x = (uint)o[0] | ((uint)o[1] << 16);
    ow.y = (uint)o[2] | ((uint)o[3] << 16);
    ow.z = (uint)o[4] | ((uint)o[5] << 16);
    ow.w = (uint)o[6] | ((uint)o[7] << 16);
    *(uint4*)(Bp + off) = ow;
}

// 512 blocks (32 g x 16 band) x 512 thr (8 waves = 4 mt x 2 halves).
template <int MODE>
__global__ __launch_bounds__(512, 4) void gat_mfma(
    const float* __restrict__ in, const ushort* __restrict__ bp,
    const float* __restrict__ att_s, const float* __restrict__ att_d,
    float* __restrict__ hlin, float* __restrict__ asrc, float* __restrict__ adst) {
    __shared__ float hbuf[64][256];        // 64KB block C-tile image
    int g = blockIdx.x >> 4, band = blockIdx.x & 15;
    int tid = threadIdx.x;
    int w = tid >> 6, lane = tid & 63;
    int mtw = w & 3;
    int mt = band * 4 + mtw;
    int half = w >> 2;                     // nt range: half*8 .. half*8+8
    bool active = (mt < 63);
    int lo = lane & 15, hi = lane >> 4;

    if (active) {
        int n = mt * 16 + lo;
        // ---- fused A load+convert: frag = x[n][kb*32 + hi*8 .. +8] ----
        float xv[16];
        if (n < NN) {
            const float* xr;
            if (MODE == 0) {
                int b = g / TT, t = g % TT;
                xr = in + (((size_t)(b * NN + n) * TT + t) * FF);
            } else {
                xr = in + ((size_t)(g * NN + n) * FF);
            }
            float4 a0 = *(const float4*)(xr + hi * 8);
            float4 a1 = *(const float4*)(xr + hi * 8 + 4);
            float4 b0 = *(const float4*)(xr + 32 + hi * 8);
            float4 b1 = *(const float4*)(xr + 32 + hi * 8 + 4);
            xv[0] = a0.x; xv[1] = a0.y; xv[2]  = a0.z; xv[3]  = a0.w;
            xv[4] = a1.x; xv[5] = a1.y; xv[6]  = a1.z; xv[7]  = a1.w;
            xv[8] = b0.x; xv[9] = b0.y; xv[10] = b0.z; xv[11] = b0.w;
            xv[12] = b1.x; xv[13] = b1.y; xv[14] = b1.z; xv[15] = b1.w;
        } else {
#pragma unroll
            for (int j = 0; j < 16; ++j) xv[j] = 0.f;
        }
        bf16x8 Ah0, Ah1, Al0, Al1;
#pragma unroll
        for (int j = 0; j < 8; ++j) {
            ushort h0 = bf16_rne(xv[j]);
            Ah0[j] = (short)h0;
            Al0[j] = (short)bf16_rne(xv[j] - __uint_as_float(((uint)h0) << 16));
            ushort h1 = bf16_rne(xv[8 + j]);
            Ah1[j] = (short)h1;
            Al1[j] = (short)bf16_rne(xv[8 + j] - __uint_as_float(((uint)h1) << 16));
        }

        size_t foff = ((size_t)(lo * 4 + hi)) * 8;
        f32x4 acc[8];
#pragma unroll
        for (int i = 0; i < 8; ++i) acc[i] = (f32x4){0.f, 0.f, 0.f, 0.f};

#pragma unroll
        for (int q = 0; q < 8; ++q) {
            int nt = half * 8 + q;
            const ushort* bb = bp + (size_t)nt * 512 + foff;
            bf16x8 Bh0 = *(const bf16x8*)(bb + 0 * 8192);
            bf16x8 Bh1 = *(const bf16x8*)(bb + 1 * 8192);
            bf16x8 Bl0 = *(const bf16x8*)(bb + 2 * 8192);
            bf16x8 Bl1 = *(const bf16x8*)(bb + 3 * 8192);
            acc[q] = __builtin_amdgcn_mfma_f32_16x16x32_bf16(Ah0, Bh0, acc[q], 0, 0, 0);
            acc[q] = __builtin_amdgcn_mfma_f32_16x16x32_bf16(Ah1, Bh1, acc[q], 0, 0, 0);
            acc[q] = __builtin_amdgcn_mfma_f32_16x16x32_bf16(Ah0, Bl0, acc[q], 0, 0, 0);
            acc[q] = __builtin_amdgcn_mfma_f32_16x16x32_bf16(Ah1, Bl1, acc[q], 0, 0, 0);
            acc[q] = __builtin_amdgcn_mfma_f32_16x16x32_bf16(Al0, Bh0, acc[q], 0, 0, 0);
            acc[q] = __builtin_amdgcn_mfma_f32_16x16x32_bf16(Al1, Bh1, acc[q], 0, 0, 0);
            acc[q] = __builtin_amdgcn_mfma_f32_16x16x32_bf16(Al0, Bl0, acc[q], 0, 0, 0);
            acc[q] = __builtin_amdgcn_mfma_f32_16x16x32_bf16(Al1, Bl1, acc[q], 0, 0, 0);
        }

        // ---- att reductions (C/D layout: col=lo, row=hi*4+reg; m89-verified) ----
        float s1[4][2], s2[4][2];
#pragma unroll
        for (int r = 0; r < 4; ++r) {
            s1[r][0] = 0.f; s1[r][1] = 0.f;
            s2[r][0] = 0.f; s2[r][1] = 0.f;
        }
#pragma unroll
        for (int q = 0; q < 8; ++q) {
            int nt = half * 8 + q;
            int c = nt * 16 + lo;
            int hh = q >> 2;
            float as = att_s[c];
            float ad = att_d[c];
#pragma unroll
            for (int reg = 0; reg < 4; ++reg) {
                float v = acc[q][reg];
                s1[reg][hh] += v * as;
                s2[reg][hh] += v * ad;
            }
        }
#pragma unroll
        for (int off = 1; off < 16; off <<= 1) {
#pragma unroll
            for (int reg = 0; reg < 4; ++reg) {
                s1[reg][0] += __shfl_xor(s1[reg][0], off, 64);
                s1[reg][1] += __shfl_xor(s1[reg][1], off, 64);
                s2[reg][0] += __shfl_xor(s2[reg][0], off, 64);
                s2[reg][1] += __shfl_xor(s2[reg][1], off, 64);
            }
        }
        if (lo == 0) {
#pragma unroll
            for (int reg = 0; reg < 4; ++reg) {
                int nr = mt * 16 + hi * 4 + reg;
                if (nr < NN) {
                    asrc[(size_t)(g * NN + nr) * NHEADS + half * 2 + 0] = s1[reg][0];
                    asrc[(size_t)(g * NN + nr) * NHEADS + half * 2 + 1] = s1[reg][1];
                    adst[(size_t)(g * NN + nr) * NHEADS + half * 2 + 0] = s2[reg][0];
                    adst[(size_t)(g * NN + nr) * NHEADS + half * 2 + 1] = s2[reg][1];
                }
            }
        }

        // ---- stage C into LDS: pair (q, q+4) -> adjacent dwords (heads h,h+1) ----
#pragma unroll
        for (int q = 0; q < 4; ++q) {
            int chan = q * 16 + lo;
#pragma unroll
            for (int reg = 0; reg < 4; ++reg) {
                int row = mtw * 16 + hi * 4 + reg;
                *(float2*)&hbuf[row][chan * 4 + half * 2] =
                    make_float2(acc[q][reg], acc[q + 4][reg]);
            }
        }
    }
    __syncthreads();

    // ---- coalesced copy-out: 64 consecutive hlin rows = 64KB linear ----
    int limit = (band == 15) ? 2560 : 4096;   // band 15: only nodes 960..999
    const float4* src = (const float4*)&hbuf[0][0];
    float4* dst = (float4*)(hlin + ((size_t)(g * NN + band * 64) << 8));
    for (int i = tid; i < limit; i += 512)
        dst[i] = src[i];
}

// ---------------- GAT edge softmax + aggregation (v4: 16-way gather ILP) ----------------
// R10 counters: 41.7us, VALUBusy 35%, FETCH 17.6MB (L2-resident gather),
// L2-BW floor ~16us -> latency-bound with only 8 gathers in flight/wave.
// v4: phase B widened to 16 independent 1KB gathers per batch (2x MLP).
// Padding to x16 safe: pbuf/sbuf zero-filled (p=0, src=0), cnt16 <= 64.
__global__ __launch_bounds__(256) void gat_edge(
    const float* __restrict__ hlin, const float* __restrict__ asrc,
    const float* __restrict__ adst, const int* __restrict__ offs,
    const int* __restrict__ csr, const float* __restrict__ bias,
    float* __restrict__ out, int do_relu) {
    __shared__ float pbuf[4][64][4];   // [wave][edge-in-chunk][head]
    __shared__ int   sbuf[4][64];
    __shared__ int   degs[4];
    int tid = threadIdx.x;
    int lane = tid & 63, w = tid >> 6;
    int B = blockIdx.x;
    int x = B & 7, j = B >> 3;             // XCD swizzle
    int graph = x + 8 * (j / 250);
    int node = graph * NN + ((j % 250) << 2) + w;
    int beg = offs[node], end = offs[node + 1];
    int deg = end - beg;
    if (lane == 0) degs[w] = deg;
    __syncthreads();
    int maxdeg = max(max(degs[0], degs[1]), max(degs[2], degs[3]));
    int nchunk = (maxdeg + 63) >> 6;

    float4 ad = *(const float4*)(adst + (size_t)node * 4);
    const float* asrc_g = asrc + (size_t)graph * NN * 4;
    const float* hg = hlin + ((size_t)graph * NN << 8);

    float4 acc = make_float4(0.f, 0.f, 0.f, 0.f);
    float4 ssum = make_float4(0.f, 0.f, 0.f, 0.f);
    for (int c = 0; c < nchunk; ++c) {
        int e0 = beg + (c << 6);
        int myedge = e0 + lane;
        float4 p = make_float4(0.f, 0.f, 0.f, 0.f);
        int src = 0;
        if (myedge < end) {
            src = csr[myedge];
            float4 a = *(const float4*)(asrc_g + (size_t)src * 4);
            p.x = __expf(leaky_(a.x + ad.x));
            p.y = __expf(leaky_(a.y + ad.y));
            p.z = __expf(leaky_(a.z + ad.z));
            p.w = __expf(leaky_(a.w + ad.w));
        }
        // butterfly sum of this chunk's weights
        float4 t = p;
#pragma unroll
        for (int off = 1; off < 64; off <<= 1) {
            t.x += __shfl_xor(t.x, off, 64);
            t.y += __shfl_xor(t.y, off, 64);
            t.z += __shfl_xor(t.z, off, 64);
            t.w += __shfl_xor(t.w, off, 64);
        }
        ssum.x += t.x; ssum.y += t.y; ssum.z += t.z; ssum.w += t.w;
        *(float4*)&pbuf[w][lane][0] = p;
        sbuf[w][lane] = src;
        __syncthreads();
        int cnt = end - e0;
        if (cnt > 64) cnt = 64;
        int cnt16 = (cnt + 15) & ~15;      // pad to x16: pbuf/sbuf zero-filled
        int lo = lane << 2;
        for (int e = 0; e < cnt16; e += 16) {
            int s[16];
#pragma unroll
            for (int i = 0; i < 16; ++i) s[i] = sbuf[w][e + i];
            float4 h[16];
#pragma unroll
            for (int i = 0; i < 16; ++i)
                h[i] = *(const float4*)(hg + (((size_t)s[i]) << 8) + lo);
#pragma unroll
            for (int i = 0; i < 16; ++i) {
                float4 p4 = *(const float4*)&pbuf[w][e + i][0];
                acc.x = fmaf(p4.x, h[i].x, acc.x);
                acc.y = fmaf(p4.y, h[i].y, acc.y);
                acc.z = fmaf(p4.z, h[i].z, acc.z);
                acc.w = fmaf(p4.w, h[i].w, acc.w);
            }
        }
        __syncthreads();
    }
    float o = 0.25f * (acc.x / ssum.x + acc.y / ssum.y + acc.z / ssum.z + acc.w / ssum.w)
            + bias[lane];
    if (do_relu) o = fmaxf(o, 0.f);
    out[((size_t)node << 6) + lane] = o;
}

// ---------------- GRU input-side GEMM ----------------
template <int MODE>
__global__ __launch_bounds__(192, 4) void gru_gi(
    const float* __restrict__ in, const float* __restrict__ Wih,
    const float* __restrict__ bih, float* __restrict__ giseq) {
    const int ROWS = 10;  // 3200 blocks * 10 = 32000 (t,row) pairs
    int j = threadIdx.x;  // 0..191
    float wrow[64];
#pragma unroll
    for (int f4 = 0; f4 < 16; ++f4) {
        float4 w = *(const float4*)(Wih + (size_t)j * 64 + f4 * 4);
        wrow[4 * f4 + 0] = w.x; wrow[4 * f4 + 1] = w.y;
        wrow[4 * f4 + 2] = w.z; wrow[4 * f4 + 3] = w.w;
    }
    PIN64_(wrow)
    float bj = bih[j];
    int q0 = blockIdx.x * ROWS;
    int t = q0 / NROWS;            // constant per block (NROWS % ROWS == 0)
    int r0 = q0 - t * NROWS;
    for (int rr = 0; rr < ROWS; rr += 2) {
        const float *xa, *xb;
        if (MODE == 0) {
            int ra = r0 + rr, rb = ra + 1;
            int ba = ra / NN, na = ra - ba * NN;
            int bb2 = rb / NN, nb = rb - bb2 * NN;
            xa = in + (((size_t)(ba * TT + t) * NN + na) << 6);
            xb = in + (((size_t)(bb2 * TT + t) * NN + nb) << 6);
        } else {
            xa = in + ((size_t)(q0 + rr) << 6);
            xb = xa + 64;
        }
        float acca = bj, accb = bj;
#pragma unroll
        for (int f4 = 0; f4 < 16; ++f4) {
            float4 a4 = *(const float4*)(xa + f4 * 4);
            float4 b4 = *(const float4*)(xb + f4 * 4);
            acca = fmaf(a4.x, wrow[4 * f4 + 0], acca);
            acca = fmaf(a4.y, wrow[4 * f4 + 1], acca);
            acca = fmaf(a4.z, wrow[4 * f4 + 2], acca);
            acca = fmaf(a4.w, wrow[4 * f4 + 3], acca);
            accb = fmaf(b4.x, wrow[4 * f4 + 0], accb);
            accb = fmaf(b4.y, wrow[4 * f4 + 1], accb);
            accb = fmaf(b4.z, wrow[4 * f4 + 2], accb);
            accb = fmaf(b4.w, wrow[4 * f4 + 3], accb);
        }
        giseq[(size_t)(q0 + rr) * 192 + j] = acca;
        giseq[(size_t)(q0 + rr + 1) * 192 + j] = accb;
    }
}

// ---------------- GRU recurrence v3 (2 rows/wave, 1000 blocks — R7 WIN) ----------------
template <int LAYER>
__global__ __launch_bounds__(128) void gru_rec(
    const float* __restrict__ giseq, const float* __restrict__ Whh,
    const float* __restrict__ bhh, float* __restrict__ outseq) {
    __shared__ float hs[4][64];       // 2 waves * 2 rows, wave-private regions
    int tid = threadIdx.x;
    int ch = tid & 63, w = tid >> 6;  // w in {0,1}
    float wr[64], wz[64], wn[64];
#pragma unroll
    for (int k4 = 0; k4 < 16; ++k4) {
        float4 a = *(const float4*)(Whh + (size_t)ch * 64 + k4 * 4);
        float4 b = *(const float4*)(Whh + (size_t)(64 + ch) * 64 + k4 * 4);
        float4 c = *(const float4*)(Whh + (size_t)(128 + ch) * 64 + k4 * 4);
        wr[4*k4+0] = a.x; wr[4*k4+1] = a.y; wr[4*k4+2] = a.z; wr[4*k4+3] = a.w;
        wz[4*k4+0] = b.x; wz[4*k4+1] = b.y; wz[4*k4+2] = b.z; wz[4*k4+3] = b.w;
        wn[4*k4+0] = c.x; wn[4*k4+1] = c.y; wn[4*k4+2] = c.z; wn[4*k4+3] = c.w;
    }
    float br = bhh[ch], bz = bhh[64 + ch], bn = bhh[128 + ch];
    int row0 = blockIdx.x * 4 + w * 2;
    float hprev[2];
#pragma unroll
    for (int r = 0; r < 2; ++r) { hs[w * 2 + r][ch] = 0.f; hprev[r] = 0.f; }

    for (int t = 0; t < TT; ++t) {
#pragma unroll
        for (int r = 0; r < 2; ++r) {
            int row = row0 + r;
            const float* gp = giseq + ((size_t)(t * NROWS + row)) * 192;
            float gir = gp[ch], giz = gp[64 + ch], gin = gp[128 + ch];
            float ar = br, az = bz, an = bn;
#pragma unroll
            for (int k4 = 0; k4 < 16; ++k4) {
                float4 h4 = *(const float4*)&hs[w * 2 + r][k4 * 4];  // broadcast
                ar = fmaf(h4.x, wr[4*k4+0], ar); ar = fmaf(h4.y, wr[4*k4+1], ar);
                ar = fmaf(h4.z, wr[4*k4+2], ar); ar = fmaf(h4.w, wr[4*k4+3], ar);
                az = fmaf(h4.x, wz[4*k4+0], az); az = fmaf(h4.y, wz[4*k4+1], az);
                az = fmaf(h4.z, wz[4*k4+2], az); az = fmaf(h4.w, wz[4*k4+3], az);
                an = fmaf(h4.x, wn[4*k4+0], an); an = fmaf(h4.y, wn[4*k4+1], an);
                an = fmaf(h4.z, wn[4*k4+2], an); an = fmaf(h4.w, wn[4*k4+3], an);
            }
            float rg = sigmoidf_(gir + ar);
            float zg = sigmoidf_(giz + az);
            float ng = tanhf_(gin + rg * an);
            float hnew = (1.f - zg) * ng + zg * hprev[r];
            hprev[r] = hnew;
            hs[w * 2 + r][ch] = hnew;
            if (LAYER == 0)
                outseq[(((size_t)(t * NROWS + row)) << 6) + ch] = hnew;
        }
    }
    if (LAYER == 1) {
#pragma unroll
        for (int r = 0; r < 2; ++r)
            outseq[(((size_t)(row0 + r)) << 6) + ch] = hprev[r];
    }
}

// ---------------- final MLP ----------------
__global__ __launch_bounds__(64) void mlp_head(
    const float* __restrict__ hT, const float* __restrict__ pW1,
    const float* __restrict__ pb1, const float* __restrict__ pW2,
    const float* __restrict__ pb2, float* __restrict__ out) {
    int r = blockIdx.x, lane = threadIdx.x;
    __shared__ float hrow[64];
    __shared__ float mid[64];
    hrow[lane] = hT[((size_t)r << 6) + lane];
    __syncthreads();
    float acc = pb1[lane];
#pragma unroll
    for (int k = 0; k < 64; ++k) acc = fmaf(hrow[k], pW1[k * 64 + lane], acc);
    mid[lane] = fmaxf(acc, 0.f);
    __syncthreads();
    if (lane < 10) {
        float o = pb2[lane];
#pragma unroll
        for (int k = 0; k < 64; ++k) o = fmaf(mid[k], pW2[k * 10 + lane], o);
        out[(size_t)r * 10 + lane] = o;
    }
}

// ---------------- launch ----------------
extern "C" void kernel_launch(void* const* d_in, const int* in_sizes, int n_in,
                              void* d_out, int out_size, void* d_ws, size_t ws_size,
                              hipStream_t stream) {
    (void)in_sizes; (void)n_in; (void)out_size; (void)ws_size;
    const float* x    = (const float*)d_in[0];
    const int*   ei   = (const int*)d_in[1];
    const float* W1   = (const float*)d_in[3];
    const float* as1  = (const float*)d_in[4];
    const float* ad1  = (const float*)d_in[5];
    const float* b1   = (const float*)d_in[6];
    const float* W2   = (const float*)d_in[7];
    const float* as2  = (const float*)d_in[8];
    const float* ad2  = (const float*)d_in[9];
    const float* b2   = (const float*)d_in[10];
    const float* Wih0 = (const float*)d_in[13];
    const float* Whh0 = (const float*)d_in[14];
    const float* bih0 = (const float*)d_in[15];
    const float* bhh0 = (const float*)d_in[16];
    const float* Wih1 = (const float*)d_in[17];
    const float* Whh1 = (const float*)d_in[18];
    const float* bih1 = (const float*)d_in[19];
    const float* bhh1 = (const float*)d_in[20];
    const float* pW1  = (const float*)d_in[21];
    const float* pb1  = (const float*)d_in[22];
    const float* pW2  = (const float*)d_in[23];
    const float* pb2  = (const float*)d_in[24];
    float* out = (float*)d_out;

    // workspace layout (bytes); overlays noted
    char* ws = (char*)d_ws;
    float* hlin  = (float*)(ws + 0);           // 32,768,000  (overlay: giseq 24.58MB)
    float* giseq = hlin;
    float* asrc  = (float*)(ws + 32768000);    // 512,000     (overlay: hT)
    float* hT    = asrc;
    float* adst  = (float*)(ws + 33280000);    // 512,000
    float* gat1  = (float*)(ws + 33792000);    // 8,192,000   (overlay: h1seq)
    float* h1seq = gat1;
    float* gat2  = (float*)(ws + 41984000);    // 8,192,000
    int* counts  = (int*)(ws + 50176000);      // 128,000
    int* cursor  = (int*)(ws + 50304000);      // 128,000
    int* offs    = (int*)(ws + 50432000);      // 128,004 (padded to 128,256)
    int* csr     = (int*)(ws + 50560256);      // 2,176,000
    ushort* Bp1  = (ushort*)(ws + 52736256);   // 65,536 (region proven safe R3/R8)
    ushort* Bp2  = (ushort*)(ws + 52801792);   // 65,536 -> total 52.87MB

    hipMemsetAsync(counts, 0, 2 * GN * sizeof(int), stream);  // counts + cursor

    dim3 egrid((E2 + 255) / 256, GG);
    count_edges<<<egrid, 256, 0, stream>>>(ei, counts);
    scan_offsets_pg<<<GG, 256, 0, stream>>>(counts, offs);
    scatter_edges<<<egrid, 256, 0, stream>>>(ei, offs, cursor, csr);

    wprep<<<128, 64, 0, stream>>>(W1, W2, Bp1, Bp2);

    gat_mfma<0><<<GG * 16, 512, 0, stream>>>(x, Bp1, as1, ad1, hlin, asrc, adst);
    gat_edge<<<GN / 4, 256, 0, stream>>>(hlin, asrc, adst, offs, csr, b1, gat1, 1);
    gat_mfma<1><<<GG * 16, 512, 0, stream>>>(gat1, Bp2, as2, ad2, hlin, asrc, adst);
    gat_edge<<<GN / 4, 256, 0, stream>>>(hlin, asrc, adst, offs, csr, b2, gat2, 0);

    gru_gi<0><<<3200, 192, 0, stream>>>(gat2, Wih0, bih0, giseq);
    gru_rec<0><<<1000, 128, 0, stream>>>(giseq, Whh0, bhh0, h1seq);
    gru_gi<1><<<3200, 192, 0, stream>>>(h1seq, Wih1, bih1, giseq);
    gru_rec<1><<<1000, 128, 0, stream>>>(giseq, Whh1, bhh1, hT);

    mlp_head<<<NROWS, 64, 0, stream>>>(hT, pW1, pb1, pW2, pb2, out);
}

// Round 13
// 391.932 us; speedup vs baseline: 1.0222x; 1.0222x over previous
//
#include <hip/hip_runtime.h>
#include <math.h>

// Problem constants
#define BB 4
#define NN 1000
#define TT 8
#define FF 64
#define HH 64
#define NHEADS 4
#define EE 16000
#define E2 17000          // EE + NN self-loops (EXACT per-graph edge total)
#define GG (BB*TT)        // 32 graphs
#define GN (GG*NN)        // 32000 (graph,node) pairs
#define NROWS (BB*NN)     // 4000 GRU rows

typedef __attribute__((ext_vector_type(8))) short bf16x8;
typedef __attribute__((ext_vector_type(4))) float f32x4;

// ---------------- helpers ----------------
__device__ __forceinline__ float sigmoidf_(float x) {
    return 1.f / (1.f + __expf(-x));
}
__device__ __forceinline__ float tanhf_(float x) {
    x = fminf(fmaxf(x, -15.f), 15.f);
    float e = __expf(2.f * x);
    return (e - 1.f) / (e + 1.f);
}
__device__ __forceinline__ float leaky_(float x) {
    return (x > 0.f) ? x : 0.2f * x;
}
__device__ __forceinline__ ushort bf16_rne(float v) {
    uint b = __float_as_uint(v);
    return (ushort)((b + 0x7FFF + ((b >> 16) & 1)) >> 16);
}

// ---------------- CSR build ----------------
__global__ void count_edges(const int* __restrict__ ei, int* __restrict__ counts) {
    int g = blockIdx.y;
    int e = blockIdx.x * 256 + threadIdx.x;
    if (e >= E2) return;
    int dst;
    if (e < EE) dst = ei[(size_t)g * 2 * EE + EE + e];
    else        dst = e - EE;   // self-loop
    atomicAdd(&counts[g * NN + dst], 1);
}

__global__ __launch_bounds__(256) void scan_offsets_pg(const int* __restrict__ counts,
                                                       int* __restrict__ offs) {
    __shared__ int tot[256];
    int g = blockIdx.x;
    int tid = threadIdx.x;
    int base = tid * 4;
    int c0 = 0, c1 = 0, c2 = 0, c3 = 0;
    if (base < NN) {
        int4 v = *(const int4*)(counts + (size_t)g * NN + base);  // 16B aligned (NN%4==0)
        c0 = v.x; c1 = v.y; c2 = v.z; c3 = v.w;
    }
    int s = c0 + c1 + c2 + c3;
    tot[tid] = s;
    __syncthreads();
    for (int off = 1; off < 256; off <<= 1) {
        int y = (tid >= off) ? tot[tid - off] : 0;
        __syncthreads();
        tot[tid] += y;
        __syncthreads();
    }
    int run = g * E2 + tot[tid] - s;  // exclusive prefix + graph base
    if (base < NN) {
        int4 o;
        o.x = run; run += c0;
        o.y = run; run += c1;
        o.z = run; run += c2;
        o.w = run;
        *(int4*)(offs + (size_t)g * NN + base) = o;
    }
    if (g == 0 && tid == 0) offs[GN] = GG * E2;
}

__global__ void scatter_edges(const int* __restrict__ ei, const int* __restrict__ offs,
                              int* __restrict__ cursor, int* __restrict__ csr) {
    int g = blockIdx.y;
    int e = blockIdx.x * 256 + threadIdx.x;
    if (e >= E2) return;
    int src, dst;
    if (e < EE) {
        src = ei[(size_t)g * 2 * EE + e];
        dst = ei[(size_t)g * 2 * EE + EE + e];
    } else {
        src = dst = e - EE;
    }
    int i = g * NN + dst;
    int pos = offs[i] + atomicAdd(&cursor[i], 1);
    csr[pos] = src;
}

// Register pin (used by gru_gi; kept frozen there)
#define PIN64_(arr)                                        \
    _Pragma("unroll")                                      \
    for (int _pi = 0; _pi < 64; ++_pi)                     \
        asm volatile("" : "+v"((arr)[_pi]));

// ---------------- MFMA GAT linear (R10: LDS-staged coalesced epilogue; FROZEN) ----------------
// Bpack per W: [wq(2)][kb(2)][nt(16)][col(16)][koct(4)][j(8)] bf16 = 64KB
__global__ __launch_bounds__(64) void wprep(
    const float* __restrict__ W1, const float* __restrict__ W2,
    ushort* __restrict__ B1, ushort* __restrict__ B2) {
    int blk = blockIdx.x;                  // 128 blocks
    const float* W = (blk >> 6) ? W2 : W1;
    ushort* Bp = (blk >> 6) ? B2 : B1;
    int r = blk & 63;
    int wq = r >> 5, kb = (r >> 4) & 1, nt = r & 15;
    int tid = threadIdx.x;                 // 64
    int col = tid >> 2, koct = tid & 3;
    int c = nt * 16 + col;
    ushort o[8];
#pragma unroll
    for (int j = 0; j < 8; ++j) {
        int k = kb * 32 + koct * 8 + j;
        float v = W[k * 256 + c];
        ushort h = bf16_rne(v);
        if (wq == 0) o[j] = h;
        else {
            float hf = __uint_as_float(((uint)h) << 16);
            o[j] = bf16_rne(v - hf);
        }
    }
    size_t off = (((size_t)((wq * 2 + kb) * 16 + nt) * 16 + col) * 4 + koct) * 8;
    uint4 ow;
    ow.x = (uint)o[0] | ((uint)o[1] << 16);
    ow.y = (uint)o[2] | ((uint)o[3] << 16);
    ow.z = (uint)o[4] | ((uint)o[5] << 16);
    ow.w = (uint)o[6] | ((uint)o[7] << 16);
    *(uint4*)(Bp + off) = ow;
}

// 512 blocks (32 g x 16 band) x 512 thr (8 waves = 4 mt x 2 halves).
template <int MODE>
__global__ __launch_bounds__(512, 4) void gat_mfma(
    const float* __restrict__ in, const ushort* __restrict__ bp,
    const float* __restrict__ att_s, const float* __restrict__ att_d,
    float* __restrict__ hlin, float* __restrict__ asrc, float* __restrict__ adst) {
    __shared__ float hbuf[64][256];        // 64KB block C-tile image
    int g = blockIdx.x >> 4, band = blockIdx.x & 15;
    int tid = threadIdx.x;
    int w = tid >> 6, lane = tid & 63;
    int mtw = w & 3;
    int mt = band * 4 + mtw;
    int half = w >> 2;                     // nt range: half*8 .. half*8+8
    bool active = (mt < 63);
    int lo = lane & 15, hi = lane >> 4;

    if (active) {
        int n = mt * 16 + lo;
        // ---- fused A load+convert: frag = x[n][kb*32 + hi*8 .. +8] ----
        float xv[16];
        if (n < NN) {
            const float* xr;
            if (MODE == 0) {
                int b = g / TT, t = g % TT;
                xr = in + (((size_t)(b * NN + n) * TT + t) * FF);
            } else {
                xr = in + ((size_t)(g * NN + n) * FF);
            }
            float4 a0 = *(const float4*)(xr + hi * 8);
            float4 a1 = *(const float4*)(xr + hi * 8 + 4);
            float4 b0 = *(const float4*)(xr + 32 + hi * 8);
            float4 b1 = *(const float4*)(xr + 32 + hi * 8 + 4);
            xv[0] = a0.x; xv[1] = a0.y; xv[2]  = a0.z; xv[3]  = a0.w;
            xv[4] = a1.x; xv[5] = a1.y; xv[6]  = a1.z; xv[7]  = a1.w;
            xv[8] = b0.x; xv[9] = b0.y; xv[10] = b0.z; xv[11] = b0.w;
            xv[12] = b1.x; xv[13] = b1.y; xv[14] = b1.z; xv[15] = b1.w;
        } else {
#pragma unroll
            for (int j = 0; j < 16; ++j) xv[j] = 0.f;
        }
        bf16x8 Ah0, Ah1, Al0, Al1;
#pragma unroll
        for (int j = 0; j < 8; ++j) {
            ushort h0 = bf16_rne(xv[j]);
            Ah0[j] = (short)h0;
            Al0[j] = (short)bf16_rne(xv[j] - __uint_as_float(((uint)h0) << 16));
            ushort h1 = bf16_rne(xv[8 + j]);
            Ah1[j] = (short)h1;
            Al1[j] = (short)bf16_rne(xv[8 + j] - __uint_as_float(((uint)h1) << 16));
        }

        size_t foff = ((size_t)(lo * 4 + hi)) * 8;
        f32x4 acc[8];
#pragma unroll
        for (int i = 0; i < 8; ++i) acc[i] = (f32x4){0.f, 0.f, 0.f, 0.f};

#pragma unroll
        for (int q = 0; q < 8; ++q) {
            int nt = half * 8 + q;
            const ushort* bb = bp + (size_t)nt * 512 + foff;
            bf16x8 Bh0 = *(const bf16x8*)(bb + 0 * 8192);
            bf16x8 Bh1 = *(const bf16x8*)(bb + 1 * 8192);
            bf16x8 Bl0 = *(const bf16x8*)(bb + 2 * 8192);
            bf16x8 Bl1 = *(const bf16x8*)(bb + 3 * 8192);
            acc[q] = __builtin_amdgcn_mfma_f32_16x16x32_bf16(Ah0, Bh0, acc[q], 0, 0, 0);
            acc[q] = __builtin_amdgcn_mfma_f32_16x16x32_bf16(Ah1, Bh1, acc[q], 0, 0, 0);
            acc[q] = __builtin_amdgcn_mfma_f32_16x16x32_bf16(Ah0, Bl0, acc[q], 0, 0, 0);
            acc[q] = __builtin_amdgcn_mfma_f32_16x16x32_bf16(Ah1, Bl1, acc[q], 0, 0, 0);
            acc[q] = __builtin_amdgcn_mfma_f32_16x16x32_bf16(Al0, Bh0, acc[q], 0, 0, 0);
            acc[q] = __builtin_amdgcn_mfma_f32_16x16x32_bf16(Al1, Bh1, acc[q], 0, 0, 0);
            acc[q] = __builtin_amdgcn_mfma_f32_16x16x32_bf16(Al0, Bl0, acc[q], 0, 0, 0);
            acc[q] = __builtin_amdgcn_mfma_f32_16x16x32_bf16(Al1, Bl1, acc[q], 0, 0, 0);
        }

        // ---- att reductions (C/D layout: col=lo, row=hi*4+reg; m89-verified) ----
        float s1[4][2], s2[4][2];
#pragma unroll
        for (int r = 0; r < 4; ++r) {
            s1[r][0] = 0.f; s1[r][1] = 0.f;
            s2[r][0] = 0.f; s2[r][1] = 0.f;
        }
#pragma unroll
        for (int q = 0; q < 8; ++q) {
            int nt = half * 8 + q;
            int c = nt * 16 + lo;
            int hh = q >> 2;
            float as = att_s[c];
            float ad = att_d[c];
#pragma unroll
            for (int reg = 0; reg < 4; ++reg) {
                float v = acc[q][reg];
                s1[reg][hh] += v * as;
                s2[reg][hh] += v * ad;
            }
        }
#pragma unroll
        for (int off = 1; off < 16; off <<= 1) {
#pragma unroll
            for (int reg = 0; reg < 4; ++reg) {
                s1[reg][0] += __shfl_xor(s1[reg][0], off, 64);
                s1[reg][1] += __shfl_xor(s1[reg][1], off, 64);
                s2[reg][0] += __shfl_xor(s2[reg][0], off, 64);
                s2[reg][1] += __shfl_xor(s2[reg][1], off, 64);
            }
        }
        if (lo == 0) {
#pragma unroll
            for (int reg = 0; reg < 4; ++reg) {
                int nr = mt * 16 + hi * 4 + reg;
                if (nr < NN) {
                    asrc[(size_t)(g * NN + nr) * NHEADS + half * 2 + 0] = s1[reg][0];
                    asrc[(size_t)(g * NN + nr) * NHEADS + half * 2 + 1] = s1[reg][1];
                    adst[(size_t)(g * NN + nr) * NHEADS + half * 2 + 0] = s2[reg][0];
                    adst[(size_t)(g * NN + nr) * NHEADS + half * 2 + 1] = s2[reg][1];
                }
            }
        }

        // ---- stage C into LDS: pair (q, q+4) -> adjacent dwords (heads h,h+1) ----
#pragma unroll
        for (int q = 0; q < 4; ++q) {
            int chan = q * 16 + lo;
#pragma unroll
            for (int reg = 0; reg < 4; ++reg) {
                int row = mtw * 16 + hi * 4 + reg;
                *(float2*)&hbuf[row][chan * 4 + half * 2] =
                    make_float2(acc[q][reg], acc[q + 4][reg]);
            }
        }
    }
    __syncthreads();

    // ---- coalesced copy-out: 64 consecutive hlin rows = 64KB linear ----
    int limit = (band == 15) ? 2560 : 4096;   // band 15: only nodes 960..999
    const float4* src = (const float4*)&hbuf[0][0];
    float4* dst = (float4*)(hlin + ((size_t)(g * NN + band * 64) << 8));
    for (int i = tid; i < limit; i += 512)
        dst[i] = src[i];
}

// ---------------- GAT edge softmax + aggregation (v5: barrier-free waves) ----------------
// R11 post-mortem: 16-way ILP hurt (compiler re-serializes; VGPR 60 not 120).
// Reverted to proven 8-way. NEW: pbuf/sbuf are WAVE-PRIVATE ([w] indexed,
// written+read by the same wave) — the per-chunk __syncthreads() and the
// degs/maxdeg convoy synchronized nothing. v5: zero barriers, per-wave
// nchunk — waves fully independent (same-wave LDS dep ordered via lgkmcnt,
// the gru_rec-proven pattern). Removes 2 barrier waits/chunk + the convoy
// on the block's max-degree node.
__global__ __launch_bounds__(256) void gat_edge(
    const float* __restrict__ hlin, const float* __restrict__ asrc,
    const float* __restrict__ adst, const int* __restrict__ offs,
    const int* __restrict__ csr, const float* __restrict__ bias,
    float* __restrict__ out, int do_relu) {
    __shared__ float pbuf[4][64][4];   // [wave][edge-in-chunk][head] — wave-private
    __shared__ int   sbuf[4][64];      // wave-private
    int tid = threadIdx.x;
    int lane = tid & 63, w = tid >> 6;
    int B = blockIdx.x;
    int x = B & 7, j = B >> 3;             // XCD swizzle
    int graph = x + 8 * (j / 250);
    int node = graph * NN + ((j % 250) << 2) + w;
    int beg = offs[node], end = offs[node + 1];
    int deg = end - beg;
    int nchunk = (deg + 63) >> 6;          // per-wave; no cross-wave convoy

    float4 ad = *(const float4*)(adst + (size_t)node * 4);
    const float* asrc_g = asrc + (size_t)graph * NN * 4;
    const float* hg = hlin + ((size_t)graph * NN << 8);

    float4 acc = make_float4(0.f, 0.f, 0.f, 0.f);
    float4 ssum = make_float4(0.f, 0.f, 0.f, 0.f);
    for (int c = 0; c < nchunk; ++c) {
        int e0 = beg + (c << 6);
        int myedge = e0 + lane;
        float4 p = make_float4(0.f, 0.f, 0.f, 0.f);
        int src = 0;
        if (myedge < end) {
            src = csr[myedge];
            float4 a = *(const float4*)(asrc_g + (size_t)src * 4);
            p.x = __expf(leaky_(a.x + ad.x));
            p.y = __expf(leaky_(a.y + ad.y));
            p.z = __expf(leaky_(a.z + ad.z));
            p.w = __expf(leaky_(a.w + ad.w));
        }
        // butterfly sum of this chunk's weights
        float4 t = p;
#pragma unroll
        for (int off = 1; off < 64; off <<= 1) {
            t.x += __shfl_xor(t.x, off, 64);
            t.y += __shfl_xor(t.y, off, 64);
            t.z += __shfl_xor(t.z, off, 64);
            t.w += __shfl_xor(t.w, off, 64);
        }
        ssum.x += t.x; ssum.y += t.y; ssum.z += t.z; ssum.w += t.w;
        *(float4*)&pbuf[w][lane][0] = p;
        sbuf[w][lane] = src;
        // no barrier: same-wave LDS write->read, ordered via lgkmcnt
        int cnt = end - e0;
        if (cnt > 64) cnt = 64;
        int cnt8 = (cnt + 7) & ~7;         // pad to x8: pbuf/sbuf zero-filled
        for (int e = 0; e < cnt8; e += 8) {
            float4 p0 = *(const float4*)&pbuf[w][e + 0][0];
            float4 p1 = *(const float4*)&pbuf[w][e + 1][0];
            float4 p2 = *(const float4*)&pbuf[w][e + 2][0];
            float4 p3 = *(const float4*)&pbuf[w][e + 3][0];
            float4 p4 = *(const float4*)&pbuf[w][e + 4][0];
            float4 p5 = *(const float4*)&pbuf[w][e + 5][0];
            float4 p6 = *(const float4*)&pbuf[w][e + 6][0];
            float4 p7 = *(const float4*)&pbuf[w][e + 7][0];
            int s0 = sbuf[w][e + 0], s1 = sbuf[w][e + 1];
            int s2 = sbuf[w][e + 2], s3 = sbuf[w][e + 3];
            int s4 = sbuf[w][e + 4], s5 = sbuf[w][e + 5];
            int s6 = sbuf[w][e + 6], s7 = sbuf[w][e + 7];
            int lo = lane << 2;
            float4 h0 = *(const float4*)(hg + (((size_t)s0) << 8) + lo);
            float4 h1 = *(const float4*)(hg + (((size_t)s1) << 8) + lo);
            float4 h2 = *(const float4*)(hg + (((size_t)s2) << 8) + lo);
            float4 h3 = *(const float4*)(hg + (((size_t)s3) << 8) + lo);
            float4 h4 = *(const float4*)(hg + (((size_t)s4) << 8) + lo);
            float4 h5 = *(const float4*)(hg + (((size_t)s5) << 8) + lo);
            float4 h6 = *(const float4*)(hg + (((size_t)s6) << 8) + lo);
            float4 h7 = *(const float4*)(hg + (((size_t)s7) << 8) + lo);
            acc.x = fmaf(p0.x, h0.x, acc.x); acc.y = fmaf(p0.y, h0.y, acc.y);
            acc.z = fmaf(p0.z, h0.z, acc.z); acc.w = fmaf(p0.w, h0.w, acc.w);
            acc.x = fmaf(p1.x, h1.x, acc.x); acc.y = fmaf(p1.y, h1.y, acc.y);
            acc.z = fmaf(p1.z, h1.z, acc.z); acc.w = fmaf(p1.w, h1.w, acc.w);
            acc.x = fmaf(p2.x, h2.x, acc.x); acc.y = fmaf(p2.y, h2.y, acc.y);
            acc.z = fmaf(p2.z, h2.z, acc.z); acc.w = fmaf(p2.w, h2.w, acc.w);
            acc.x = fmaf(p3.x, h3.x, acc.x); acc.y = fmaf(p3.y, h3.y, acc.y);
            acc.z = fmaf(p3.z, h3.z, acc.z); acc.w = fmaf(p3.w, h3.w, acc.w);
            acc.x = fmaf(p4.x, h4.x, acc.x); acc.y = fmaf(p4.y, h4.y, acc.y);
            acc.z = fmaf(p4.z, h4.z, acc.z); acc.w = fmaf(p4.w, h4.w, acc.w);
            acc.x = fmaf(p5.x, h5.x, acc.x); acc.y = fmaf(p5.y, h5.y, acc.y);
            acc.z = fmaf(p5.z, h5.z, acc.z); acc.w = fmaf(p5.w, h5.w, acc.w);
            acc.x = fmaf(p6.x, h6.x, acc.x); acc.y = fmaf(p6.y, h6.y, acc.y);
            acc.z = fmaf(p6.z, h6.z, acc.z); acc.w = fmaf(p6.w, h6.w, acc.w);
            acc.x = fmaf(p7.x, h7.x, acc.x); acc.y = fmaf(p7.y, h7.y, acc.y);
            acc.z = fmaf(p7.z, h7.z, acc.z); acc.w = fmaf(p7.w, h7.w, acc.w);
        }
        // no barrier: next chunk's writes follow this wave's reads in order
    }
    float o = 0.25f * (acc.x / ssum.x + acc.y / ssum.y + acc.z / ssum.z + acc.w / ssum.w)
            + bias[lane];
    if (do_relu) o = fmaxf(o, 0.f);
    out[((size_t)node << 6) + lane] = o;
}

// ---------------- GRU input-side GEMM ----------------
template <int MODE>
__global__ __launch_bounds__(192, 4) void gru_gi(
    const float* __restrict__ in, const float* __restrict__ Wih,
    const float* __restrict__ bih, float* __restrict__ giseq) {
    const int ROWS = 10;  // 3200 blocks * 10 = 32000 (t,row) pairs
    int j = threadIdx.x;  // 0..191
    float wrow[64];
#pragma unroll
    for (int f4 = 0; f4 < 16; ++f4) {
        float4 w = *(const float4*)(Wih + (size_t)j * 64 + f4 * 4);
        wrow[4 * f4 + 0] = w.x; wrow[4 * f4 + 1] = w.y;
        wrow[4 * f4 + 2] = w.z; wrow[4 * f4 + 3] = w.w;
    }
    PIN64_(wrow)
    float bj = bih[j];
    int q0 = blockIdx.x * ROWS;
    int t = q0 / NROWS;            // constant per block (NROWS % ROWS == 0)
    int r0 = q0 - t * NROWS;
    for (int rr = 0; rr < ROWS; rr += 2) {
        const float *xa, *xb;
        if (MODE == 0) {
            int ra = r0 + rr, rb = ra + 1;
            int ba = ra / NN, na = ra - ba * NN;
            int bb2 = rb / NN, nb = rb - bb2 * NN;
            xa = in + (((size_t)(ba * TT + t) * NN + na) << 6);
            xb = in + (((size_t)(bb2 * TT + t) * NN + nb) << 6);
        } else {
            xa = in + ((size_t)(q0 + rr) << 6);
            xb = xa + 64;
        }
        float acca = bj, accb = bj;
#pragma unroll
        for (int f4 = 0; f4 < 16; ++f4) {
            float4 a4 = *(const float4*)(xa + f4 * 4);
            float4 b4 = *(const float4*)(xb + f4 * 4);
            acca = fmaf(a4.x, wrow[4 * f4 + 0], acca);
            acca = fmaf(a4.y, wrow[4 * f4 + 1], acca);
            acca = fmaf(a4.z, wrow[4 * f4 + 2], acca);
            acca = fmaf(a4.w, wrow[4 * f4 + 3], acca);
            accb = fmaf(b4.x, wrow[4 * f4 + 0], accb);
            accb = fmaf(b4.y, wrow[4 * f4 + 1], accb);
            accb = fmaf(b4.z, wrow[4 * f4 + 2], accb);
            accb = fmaf(b4.w, wrow[4 * f4 + 3], accb);
        }
        giseq[(size_t)(q0 + rr) * 192 + j] = acca;
        giseq[(size_t)(q0 + rr + 1) * 192 + j] = accb;
    }
}

// ---------------- GRU recurrence v3 (2 rows/wave, 1000 blocks — R7 WIN) ----------------
template <int LAYER>
__global__ __launch_bounds__(128) void gru_rec(
    const float* __restrict__ giseq, const float* __restrict__ Whh,
    const float* __restrict__ bhh, float* __restrict__ outseq) {
    __shared__ float hs[4][64];       // 2 waves * 2 rows, wave-private regions
    int tid = threadIdx.x;
    int ch = tid & 63, w = tid >> 6;  // w in {0,1}
    float wr[64], wz[64], wn[64];
#pragma unroll
    for (int k4 = 0; k4 < 16; ++k4) {
        float4 a = *(const float4*)(Whh + (size_t)ch * 64 + k4 * 4);
        float4 b = *(const float4*)(Whh + (size_t)(64 + ch) * 64 + k4 * 4);
        float4 c = *(const float4*)(Whh + (size_t)(128 + ch) * 64 + k4 * 4);
        wr[4*k4+0] = a.x; wr[4*k4+1] = a.y; wr[4*k4+2] = a.z; wr[4*k4+3] = a.w;
        wz[4*k4+0] = b.x; wz[4*k4+1] = b.y; wz[4*k4+2] = b.z; wz[4*k4+3] = b.w;
        wn[4*k4+0] = c.x; wn[4*k4+1] = c.y; wn[4*k4+2] = c.z; wn[4*k4+3] = c.w;
    }
    float br = bhh[ch], bz = bhh[64 + ch], bn = bhh[128 + ch];
    int row0 = blockIdx.x * 4 + w * 2;
    float hprev[2];
#pragma unroll
    for (int r = 0; r < 2; ++r) { hs[w * 2 + r][ch] = 0.f; hprev[r] = 0.f; }

    for (int t = 0; t < TT; ++t) {
#pragma unroll
        for (int r = 0; r < 2; ++r) {
            int row = row0 + r;
            const float* gp = giseq + ((size_t)(t * NROWS + row)) * 192;
            float gir = gp[ch], giz = gp[64 + ch], gin = gp[128 + ch];
            float ar = br, az = bz, an = bn;
#pragma unroll
            for (int k4 = 0; k4 < 16; ++k4) {
                float4 h4 = *(const float4*)&hs[w * 2 + r][k4 * 4];  // broadcast
                ar = fmaf(h4.x, wr[4*k4+0], ar); ar = fmaf(h4.y, wr[4*k4+1], ar);
                ar = fmaf(h4.z, wr[4*k4+2], ar); ar = fmaf(h4.w, wr[4*k4+3], ar);
                az = fmaf(h4.x, wz[4*k4+0], az); az = fmaf(h4.y, wz[4*k4+1], az);
                az = fmaf(h4.z, wz[4*k4+2], az); az = fmaf(h4.w, wz[4*k4+3], az);
                an = fmaf(h4.x, wn[4*k4+0], an); an = fmaf(h4.y, wn[4*k4+1], an);
                an = fmaf(h4.z, wn[4*k4+2], an); an = fmaf(h4.w, wn[4*k4+3], an);
            }
            float rg = sigmoidf_(gir + ar);
            float zg = sigmoidf_(giz + az);
            float ng = tanhf_(gin + rg * an);
            float hnew = (1.f - zg) * ng + zg * hprev[r];
            hprev[r] = hnew;
            hs[w * 2 + r][ch] = hnew;
            if (LAYER == 0)
                outseq[(((size_t)(t * NROWS + row)) << 6) + ch] = hnew;
        }
    }
    if (LAYER == 1) {
#pragma unroll
        for (int r = 0; r < 2; ++r)
            outseq[(((size_t)(row0 + r)) << 6) + ch] = hprev[r];
    }
}

// ---------------- final MLP ----------------
__global__ __launch_bounds__(64) void mlp_head(
    const float* __restrict__ hT, const float* __restrict__ pW1,
    const float* __restrict__ pb1, const float* __restrict__ pW2,
    const float* __restrict__ pb2, float* __restrict__ out) {
    int r = blockIdx.x, lane = threadIdx.x;
    __shared__ float hrow[64];
    __shared__ float mid[64];
    hrow[lane] = hT[((size_t)r << 6) + lane];
    __syncthreads();
    float acc = pb1[lane];
#pragma unroll
    for (int k = 0; k < 64; ++k) acc = fmaf(hrow[k], pW1[k * 64 + lane], acc);
    mid[lane] = fmaxf(acc, 0.f);
    __syncthreads();
    if (lane < 10) {
        float o = pb2[lane];
#pragma unroll
        for (int k = 0; k < 64; ++k) o = fmaf(mid[k], pW2[k * 10 + lane], o);
        out[(size_t)r * 10 + lane] = o;
    }
}

// ---------------- launch ----------------
extern "C" void kernel_launch(void* const* d_in, const int* in_sizes, int n_in,
                              void* d_out, int out_size, void* d_ws, size_t ws_size,
                              hipStream_t stream) {
    (void)in_sizes; (void)n_in; (void)out_size; (void)ws_size;
    const float* x    = (const float*)d_in[0];
    const int*   ei   = (const int*)d_in[1];
    const float* W1   = (const float*)d_in[3];
    const float* as1  = (const float*)d_in[4];
    const float* ad1  = (const float*)d_in[5];
    const float* b1   = (const float*)d_in[6];
    const float* W2   = (const float*)d_in[7];
    const float* as2  = (const float*)d_in[8];
    const float* ad2  = (const float*)d_in[9];
    const float* b2   = (const float*)d_in[10];
    const float* Wih0 = (const float*)d_in[13];
    const float* Whh0 = (const float*)d_in[14];
    const float* bih0 = (const float*)d_in[15];
    const float* bhh0 = (const float*)d_in[16];
    const float* Wih1 = (const float*)d_in[17];
    const float* Whh1 = (const float*)d_in[18];
    const float* bih1 = (const float*)d_in[19];
    const float* bhh1 = (const float*)d_in[20];
    const float* pW1  = (const float*)d_in[21];
    const float* pb1  = (const float*)d_in[22];
    const float* pW2  = (const float*)d_in[23];
    const float* pb2  = (const float*)d_in[24];
    float* out = (float*)d_out;

    // workspace layout (bytes); overlays noted
    char* ws = (char*)d_ws;
    float* hlin  = (float*)(ws + 0);           // 32,768,000  (overlay: giseq 24.58MB)
    float* giseq = hlin;
    float* asrc  = (float*)(ws + 32768000);    // 512,000     (overlay: hT)
    float* hT    = asrc;
    float* adst  = (float*)(ws + 33280000);    // 512,000
    float* gat1  = (float*)(ws + 33792000);    // 8,192,000   (overlay: h1seq)
    float* h1seq = gat1;
    float* gat2  = (float*)(ws + 41984000);    // 8,192,000
    int* counts  = (int*)(ws + 50176000);      // 128,000
    int* cursor  = (int*)(ws + 50304000);      // 128,000
    int* offs    = (int*)(ws + 50432000);      // 128,004 (padded to 128,256)
    int* csr     = (int*)(ws + 50560256);      // 2,176,000
    ushort* Bp1  = (ushort*)(ws + 52736256);   // 65,536 (region proven safe R3/R8)
    ushort* Bp2  = (ushort*)(ws + 52801792);   // 65,536 -> total 52.87MB

    hipMemsetAsync(counts, 0, 2 * GN * sizeof(int), stream);  // counts + cursor

    dim3 egrid((E2 + 255) / 256, GG);
    count_edges<<<egrid, 256, 0, stream>>>(ei, counts);
    scan_offsets_pg<<<GG, 256, 0, stream>>>(counts, offs);
    scatter_edges<<<egrid, 256, 0, stream>>>(ei, offs, cursor, csr);

    wprep<<<128, 64, 0, stream>>>(W1, W2, Bp1, Bp2);

    gat_mfma<0><<<GG * 16, 512, 0, stream>>>(x, Bp1, as1, ad1, hlin, asrc, adst);
    gat_edge<<<GN / 4, 256, 0, stream>>>(hlin, asrc, adst, offs, csr, b1, gat1, 1);
    gat_mfma<1><<<GG * 16, 512, 0, stream>>>(gat1, Bp2, as2, ad2, hlin, asrc, adst);
    gat_edge<<<GN / 4, 256, 0, stream>>>(hlin, asrc, adst, offs, csr, b2, gat2, 0);

    gru_gi<0><<<3200, 192, 0, stream>>>(gat2, Wih0, bih0, giseq);
    gru_rec<0><<<1000, 128, 0, stream>>>(giseq, Whh0, bhh0, h1seq);
    gru_gi<1><<<3200, 192, 0, stream>>>(h1seq, Wih1, bih1, giseq);
    gru_rec<1><<<1000, 128, 0, stream>>>(giseq, Whh1, bhh1, hT);

    mlp_head<<<NROWS, 64, 0, stream>>>(hT, pW1, pb1, pW2, pb2, out);
}

// Round 14
// 382.721 us; speedup vs baseline: 1.0468x; 1.0241x over previous
//
#include <hip/hip_runtime.h>
#include <hip/hip_fp16.h>
#include <math.h>

// Problem constants
#define BB 4
#define NN 1000
#define TT 8
#define FF 64
#define HH 64
#define NHEADS 4
#define EE 16000
#define E2 17000          // EE + NN self-loops (EXACT per-graph edge total)
#define GG (BB*TT)        // 32 graphs
#define GN (GG*NN)        // 32000 (graph,node) pairs
#define NROWS (BB*NN)     // 4000 GRU rows

typedef __attribute__((ext_vector_type(8))) short bf16x8;
typedef __attribute__((ext_vector_type(4))) float f32x4;

// ---------------- helpers ----------------
__device__ __forceinline__ float sigmoidf_(float x) {
    return 1.f / (1.f + __expf(-x));
}
__device__ __forceinline__ float tanhf_(float x) {
    x = fminf(fmaxf(x, -15.f), 15.f);
    float e = __expf(2.f * x);
    return (e - 1.f) / (e + 1.f);
}
__device__ __forceinline__ float leaky_(float x) {
    return (x > 0.f) ? x : 0.2f * x;
}
__device__ __forceinline__ ushort bf16_rne(float v) {
    uint b = __float_as_uint(v);
    return (ushort)((b + 0x7FFF + ((b >> 16) & 1)) >> 16);
}
__device__ __forceinline__ uint pack_h2(float a, float b) {
    uint lo = (uint)__half_as_ushort(__float2half_rn(a));
    uint hi = (uint)__half_as_ushort(__float2half_rn(b));
    return lo | (hi << 16);
}
__device__ __forceinline__ float4 load_h4(const ushort* p) {
    uint2 v = *(const uint2*)p;
    __half2 a = *(__half2*)&v.x, b = *(__half2*)&v.y;
    float2 fa = __half22float2(a), fb = __half22float2(b);
    return make_float4(fa.x, fa.y, fb.x, fb.y);
}

// ---------------- CSR build ----------------
__global__ void count_edges(const int* __restrict__ ei, int* __restrict__ counts) {
    int g = blockIdx.y;
    int e = blockIdx.x * 256 + threadIdx.x;
    if (e >= E2) return;
    int dst;
    if (e < EE) dst = ei[(size_t)g * 2 * EE + EE + e];
    else        dst = e - EE;   // self-loop
    atomicAdd(&counts[g * NN + dst], 1);
}

__global__ __launch_bounds__(256) void scan_offsets_pg(const int* __restrict__ counts,
                                                       int* __restrict__ offs) {
    __shared__ int tot[256];
    int g = blockIdx.x;
    int tid = threadIdx.x;
    int base = tid * 4;
    int c0 = 0, c1 = 0, c2 = 0, c3 = 0;
    if (base < NN) {
        int4 v = *(const int4*)(counts + (size_t)g * NN + base);  // 16B aligned (NN%4==0)
        c0 = v.x; c1 = v.y; c2 = v.z; c3 = v.w;
    }
    int s = c0 + c1 + c2 + c3;
    tot[tid] = s;
    __syncthreads();
    for (int off = 1; off < 256; off <<= 1) {
        int y = (tid >= off) ? tot[tid - off] : 0;
        __syncthreads();
        tot[tid] += y;
        __syncthreads();
    }
    int run = g * E2 + tot[tid] - s;  // exclusive prefix + graph base
    if (base < NN) {
        int4 o;
        o.x = run; run += c0;
        o.y = run; run += c1;
        o.z = run; run += c2;
        o.w = run;
        *(int4*)(offs + (size_t)g * NN + base) = o;
    }
    if (g == 0 && tid == 0) offs[GN] = GG * E2;
}

__global__ void scatter_edges(const int* __restrict__ ei, const int* __restrict__ offs,
                              int* __restrict__ cursor, int* __restrict__ csr) {
    int g = blockIdx.y;
    int e = blockIdx.x * 256 + threadIdx.x;
    if (e >= E2) return;
    int src, dst;
    if (e < EE) {
        src = ei[(size_t)g * 2 * EE + e];
        dst = ei[(size_t)g * 2 * EE + EE + e];
    } else {
        src = dst = e - EE;
    }
    int i = g * NN + dst;
    int pos = offs[i] + atomicAdd(&cursor[i], 1);
    csr[pos] = src;
}

// Register pin (used by gru_gi; kept frozen there)
#define PIN64_(arr)                                        \
    _Pragma("unroll")                                      \
    for (int _pi = 0; _pi < 64; ++_pi)                     \
        asm volatile("" : "+v"((arr)[_pi]));

// ---------------- MFMA GAT linear (R13: fp16 hlin output) ----------------
// R12 counters: gat_edge at ~39us = L3-BW bound (544MB logical gather;
// 16.4MB/graph >> 4MB XCD L2 -> served from L3 at ~14TB/s ~= 39us; NOT
// latency — which is why R11's ILP widening failed). Only lever: move
// fewer bytes. hlin stored as fp16 (rel err ~5e-4, convex-combination
// consumer) -> gather traffic halves. MFMA math unchanged (R8-verified).

// Bpack per W: [wq(2)][kb(2)][nt(16)][col(16)][koct(4)][j(8)] bf16 = 64KB
__global__ __launch_bounds__(64) void wprep(
    const float* __restrict__ W1, const float* __restrict__ W2,
    ushort* __restrict__ B1, ushort* __restrict__ B2) {
    int blk = blockIdx.x;                  // 128 blocks
    const float* W = (blk >> 6) ? W2 : W1;
    ushort* Bp = (blk >> 6) ? B2 : B1;
    int r = blk & 63;
    int wq = r >> 5, kb = (r >> 4) & 1, nt = r & 15;
    int tid = threadIdx.x;                 // 64
    int col = tid >> 2, koct = tid & 3;
    int c = nt * 16 + col;
    ushort o[8];
#pragma unroll
    for (int j = 0; j < 8; ++j) {
        int k = kb * 32 + koct * 8 + j;
        float v = W[k * 256 + c];
        ushort h = bf16_rne(v);
        if (wq == 0) o[j] = h;
        else {
            float hf = __uint_as_float(((uint)h) << 16);
            o[j] = bf16_rne(v - hf);
        }
    }
    size_t off = (((size_t)((wq * 2 + kb) * 16 + nt) * 16 + col) * 4 + koct) * 8;
    uint4 ow;
    ow.x = (uint)o[0] | ((uint)o[1] << 16);
    ow.y = (uint)o[2] | ((uint)o[3] << 16);
    ow.z = (uint)o[4] | ((uint)o[5] << 16);
    ow.w = (uint)o[6] | ((uint)o[7] << 16);
    *(uint4*)(Bp + off) = ow;
}

// 512 blocks (32 g x 16 band) x 512 thr (8 waves = 4 mt x 2 halves).
template <int MODE>
__global__ __launch_bounds__(512, 4) void gat_mfma(
    const float* __restrict__ in, const ushort* __restrict__ bp,
    const float* __restrict__ att_s, const float* __restrict__ att_d,
    ushort* __restrict__ hlin, float* __restrict__ asrc, float* __restrict__ adst) {
    __shared__ float hbuf[64][256];        // 64KB block C-tile image
    int g = blockIdx.x >> 4, band = blockIdx.x & 15;
    int tid = threadIdx.x;
    int w = tid >> 6, lane = tid & 63;
    int mtw = w & 3;
    int mt = band * 4 + mtw;
    int half = w >> 2;                     // nt range: half*8 .. half*8+8
    bool active = (mt < 63);
    int lo = lane & 15, hi = lane >> 4;

    if (active) {
        int n = mt * 16 + lo;
        // ---- fused A load+convert: frag = x[n][kb*32 + hi*8 .. +8] ----
        float xv[16];
        if (n < NN) {
            const float* xr;
            if (MODE == 0) {
                int b = g / TT, t = g % TT;
                xr = in + (((size_t)(b * NN + n) * TT + t) * FF);
            } else {
                xr = in + ((size_t)(g * NN + n) * FF);
            }
            float4 a0 = *(const float4*)(xr + hi * 8);
            float4 a1 = *(const float4*)(xr + hi * 8 + 4);
            float4 b0 = *(const float4*)(xr + 32 + hi * 8);
            float4 b1 = *(const float4*)(xr + 32 + hi * 8 + 4);
            xv[0] = a0.x; xv[1] = a0.y; xv[2]  = a0.z; xv[3]  = a0.w;
            xv[4] = a1.x; xv[5] = a1.y; xv[6]  = a1.z; xv[7]  = a1.w;
            xv[8] = b0.x; xv[9] = b0.y; xv[10] = b0.z; xv[11] = b0.w;
            xv[12] = b1.x; xv[13] = b1.y; xv[14] = b1.z; xv[15] = b1.w;
        } else {
#pragma unroll
            for (int j = 0; j < 16; ++j) xv[j] = 0.f;
        }
        bf16x8 Ah0, Ah1, Al0, Al1;
#pragma unroll
        for (int j = 0; j < 8; ++j) {
            ushort h0 = bf16_rne(xv[j]);
            Ah0[j] = (short)h0;
            Al0[j] = (short)bf16_rne(xv[j] - __uint_as_float(((uint)h0) << 16));
            ushort h1 = bf16_rne(xv[8 + j]);
            Ah1[j] = (short)h1;
            Al1[j] = (short)bf16_rne(xv[8 + j] - __uint_as_float(((uint)h1) << 16));
        }

        size_t foff = ((size_t)(lo * 4 + hi)) * 8;
        f32x4 acc[8];
#pragma unroll
        for (int i = 0; i < 8; ++i) acc[i] = (f32x4){0.f, 0.f, 0.f, 0.f};

#pragma unroll
        for (int q = 0; q < 8; ++q) {
            int nt = half * 8 + q;
            const ushort* bb = bp + (size_t)nt * 512 + foff;
            bf16x8 Bh0 = *(const bf16x8*)(bb + 0 * 8192);
            bf16x8 Bh1 = *(const bf16x8*)(bb + 1 * 8192);
            bf16x8 Bl0 = *(const bf16x8*)(bb + 2 * 8192);
            bf16x8 Bl1 = *(const bf16x8*)(bb + 3 * 8192);
            acc[q] = __builtin_amdgcn_mfma_f32_16x16x32_bf16(Ah0, Bh0, acc[q], 0, 0, 0);
            acc[q] = __builtin_amdgcn_mfma_f32_16x16x32_bf16(Ah1, Bh1, acc[q], 0, 0, 0);
            acc[q] = __builtin_amdgcn_mfma_f32_16x16x32_bf16(Ah0, Bl0, acc[q], 0, 0, 0);
            acc[q] = __builtin_amdgcn_mfma_f32_16x16x32_bf16(Ah1, Bl1, acc[q], 0, 0, 0);
            acc[q] = __builtin_amdgcn_mfma_f32_16x16x32_bf16(Al0, Bh0, acc[q], 0, 0, 0);
            acc[q] = __builtin_amdgcn_mfma_f32_16x16x32_bf16(Al1, Bh1, acc[q], 0, 0, 0);
            acc[q] = __builtin_amdgcn_mfma_f32_16x16x32_bf16(Al0, Bl0, acc[q], 0, 0, 0);
            acc[q] = __builtin_amdgcn_mfma_f32_16x16x32_bf16(Al1, Bl1, acc[q], 0, 0, 0);
        }

        // ---- att reductions (C/D layout: col=lo, row=hi*4+reg; m89-verified) ----
        float s1[4][2], s2[4][2];
#pragma unroll
        for (int r = 0; r < 4; ++r) {
            s1[r][0] = 0.f; s1[r][1] = 0.f;
            s2[r][0] = 0.f; s2[r][1] = 0.f;
        }
#pragma unroll
        for (int q = 0; q < 8; ++q) {
            int nt = half * 8 + q;
            int c = nt * 16 + lo;
            int hh = q >> 2;
            float as = att_s[c];
            float ad = att_d[c];
#pragma unroll
            for (int reg = 0; reg < 4; ++reg) {
                float v = acc[q][reg];
                s1[reg][hh] += v * as;
                s2[reg][hh] += v * ad;
            }
        }
#pragma unroll
        for (int off = 1; off < 16; off <<= 1) {
#pragma unroll
            for (int reg = 0; reg < 4; ++reg) {
                s1[reg][0] += __shfl_xor(s1[reg][0], off, 64);
                s1[reg][1] += __shfl_xor(s1[reg][1], off, 64);
                s2[reg][0] += __shfl_xor(s2[reg][0], off, 64);
                s2[reg][1] += __shfl_xor(s2[reg][1], off, 64);
            }
        }
        if (lo == 0) {
#pragma unroll
            for (int reg = 0; reg < 4; ++reg) {
                int nr = mt * 16 + hi * 4 + reg;
                if (nr < NN) {
                    asrc[(size_t)(g * NN + nr) * NHEADS + half * 2 + 0] = s1[reg][0];
                    asrc[(size_t)(g * NN + nr) * NHEADS + half * 2 + 1] = s1[reg][1];
                    adst[(size_t)(g * NN + nr) * NHEADS + half * 2 + 0] = s2[reg][0];
                    adst[(size_t)(g * NN + nr) * NHEADS + half * 2 + 1] = s2[reg][1];
                }
            }
        }

        // ---- stage C into LDS: pair (q, q+4) -> adjacent dwords (heads h,h+1) ----
#pragma unroll
        for (int q = 0; q < 4; ++q) {
            int chan = q * 16 + lo;
#pragma unroll
            for (int reg = 0; reg < 4; ++reg) {
                int row = mtw * 16 + hi * 4 + reg;
                *(float2*)&hbuf[row][chan * 4 + half * 2] =
                    make_float2(acc[q][reg], acc[q + 4][reg]);
            }
        }
    }
    __syncthreads();

    // ---- coalesced fp16 copy-out: 64 rows x 256 halves = 32KB linear ----
    int limit8 = (band == 15) ? 1280 : 2048;   // groups of 8 halves (band 15: 40 rows)
    const float* src = &hbuf[0][0];
    ushort* dst = hlin + ((size_t)(g * NN + band * 64) << 8);
    for (int i = tid; i < limit8; i += 512) {
        const float* s = src + i * 8;
        uint4 ow;
        ow.x = pack_h2(s[0], s[1]);
        ow.y = pack_h2(s[2], s[3]);
        ow.z = pack_h2(s[4], s[5]);
        ow.w = pack_h2(s[6], s[7]);
        *(uint4*)(dst + i * 8) = ow;
    }
}

// ---------------- GAT edge softmax + aggregation (v6: fp16 gather, barrier-free) ----------------
__global__ __launch_bounds__(256) void gat_edge(
    const ushort* __restrict__ hlin, const float* __restrict__ asrc,
    const float* __restrict__ adst, const int* __restrict__ offs,
    const int* __restrict__ csr, const float* __restrict__ bias,
    float* __restrict__ out, int do_relu) {
    __shared__ float pbuf[4][64][4];   // [wave][edge-in-chunk][head] — wave-private
    __shared__ int   sbuf[4][64];      // wave-private
    int tid = threadIdx.x;
    int lane = tid & 63, w = tid >> 6;
    int B = blockIdx.x;
    int x = B & 7, j = B >> 3;             // XCD swizzle
    int graph = x + 8 * (j / 250);
    int node = graph * NN + ((j % 250) << 2) + w;
    int beg = offs[node], end = offs[node + 1];
    int deg = end - beg;
    int nchunk = (deg + 63) >> 6;          // per-wave; no cross-wave convoy

    float4 ad = *(const float4*)(adst + (size_t)node * 4);
    const float* asrc_g = asrc + (size_t)graph * NN * 4;
    const ushort* hg = hlin + ((size_t)graph * NN << 8);

    float4 acc = make_float4(0.f, 0.f, 0.f, 0.f);
    float4 ssum = make_float4(0.f, 0.f, 0.f, 0.f);
    for (int c = 0; c < nchunk; ++c) {
        int e0 = beg + (c << 6);
        int myedge = e0 + lane;
        float4 p = make_float4(0.f, 0.f, 0.f, 0.f);
        int src = 0;
        if (myedge < end) {
            src = csr[myedge];
            float4 a = *(const float4*)(asrc_g + (size_t)src * 4);
            p.x = __expf(leaky_(a.x + ad.x));
            p.y = __expf(leaky_(a.y + ad.y));
            p.z = __expf(leaky_(a.z + ad.z));
            p.w = __expf(leaky_(a.w + ad.w));
        }
        // butterfly sum of this chunk's weights
        float4 t = p;
#pragma unroll
        for (int off = 1; off < 64; off <<= 1) {
            t.x += __shfl_xor(t.x, off, 64);
            t.y += __shfl_xor(t.y, off, 64);
            t.z += __shfl_xor(t.z, off, 64);
            t.w += __shfl_xor(t.w, off, 64);
        }
        ssum.x += t.x; ssum.y += t.y; ssum.z += t.z; ssum.w += t.w;
        *(float4*)&pbuf[w][lane][0] = p;
        sbuf[w][lane] = src;
        // no barrier: same-wave LDS write->read, ordered via lgkmcnt
        int cnt = end - e0;
        if (cnt > 64) cnt = 64;
        int cnt8 = (cnt + 7) & ~7;         // pad to x8: pbuf/sbuf zero-filled
        for (int e = 0; e < cnt8; e += 8) {
            float4 p0 = *(const float4*)&pbuf[w][e + 0][0];
            float4 p1 = *(const float4*)&pbuf[w][e + 1][0];
            float4 p2 = *(const float4*)&pbuf[w][e + 2][0];
            float4 p3 = *(const float4*)&pbuf[w][e + 3][0];
            float4 p4 = *(const float4*)&pbuf[w][e + 4][0];
            float4 p5 = *(const float4*)&pbuf[w][e + 5][0];
            float4 p6 = *(const float4*)&pbuf[w][e + 6][0];
            float4 p7 = *(const float4*)&pbuf[w][e + 7][0];
            int s0 = sbuf[w][e + 0], s1 = sbuf[w][e + 1];
            int s2 = sbuf[w][e + 2], s3 = sbuf[w][e + 3];
            int s4 = sbuf[w][e + 4], s5 = sbuf[w][e + 5];
            int s6 = sbuf[w][e + 6], s7 = sbuf[w][e + 7];
            int lo = lane << 2;                // half index within row
            float4 h0 = load_h4(hg + (((size_t)s0) << 8) + lo);
            float4 h1 = load_h4(hg + (((size_t)s1) << 8) + lo);
            float4 h2 = load_h4(hg + (((size_t)s2) << 8) + lo);
            float4 h3 = load_h4(hg + (((size_t)s3) << 8) + lo);
            float4 h4 = load_h4(hg + (((size_t)s4) << 8) + lo);
            float4 h5 = load_h4(hg + (((size_t)s5) << 8) + lo);
            float4 h6 = load_h4(hg + (((size_t)s6) << 8) + lo);
            float4 h7 = load_h4(hg + (((size_t)s7) << 8) + lo);
            acc.x = fmaf(p0.x, h0.x, acc.x); acc.y = fmaf(p0.y, h0.y, acc.y);
            acc.z = fmaf(p0.z, h0.z, acc.z); acc.w = fmaf(p0.w, h0.w, acc.w);
            acc.x = fmaf(p1.x, h1.x, acc.x); acc.y = fmaf(p1.y, h1.y, acc.y);
            acc.z = fmaf(p1.z, h1.z, acc.z); acc.w = fmaf(p1.w, h1.w, acc.w);
            acc.x = fmaf(p2.x, h2.x, acc.x); acc.y = fmaf(p2.y, h2.y, acc.y);
            acc.z = fmaf(p2.z, h2.z, acc.z); acc.w = fmaf(p2.w, h2.w, acc.w);
            acc.x = fmaf(p3.x, h3.x, acc.x); acc.y = fmaf(p3.y, h3.y, acc.y);
            acc.z = fmaf(p3.z, h3.z, acc.z); acc.w = fmaf(p3.w, h3.w, acc.w);
            acc.x = fmaf(p4.x, h4.x, acc.x); acc.y = fmaf(p4.y, h4.y, acc.y);
            acc.z = fmaf(p4.z, h4.z, acc.z); acc.w = fmaf(p4.w, h4.w, acc.w);
            acc.x = fmaf(p5.x, h5.x, acc.x); acc.y = fmaf(p5.y, h5.y, acc.y);
            acc.z = fmaf(p5.z, h5.z, acc.z); acc.w = fmaf(p5.w, h5.w, acc.w);
            acc.x = fmaf(p6.x, h6.x, acc.x); acc.y = fmaf(p6.y, h6.y, acc.y);
            acc.z = fmaf(p6.z, h6.z, acc.z); acc.w = fmaf(p6.w, h6.w, acc.w);
            acc.x = fmaf(p7.x, h7.x, acc.x); acc.y = fmaf(p7.y, h7.y, acc.y);
            acc.z = fmaf(p7.z, h7.z, acc.z); acc.w = fmaf(p7.w, h7.w, acc.w);
        }
        // no barrier: next chunk's writes follow this wave's reads in order
    }
    float o = 0.25f * (acc.x / ssum.x + acc.y / ssum.y + acc.z / ssum.z + acc.w / ssum.w)
            + bias[lane];
    if (do_relu) o = fmaxf(o, 0.f);
    out[((size_t)node << 6) + lane] = o;
}

// ---------------- GRU input-side GEMM ----------------
template <int MODE>
__global__ __launch_bounds__(192, 4) void gru_gi(
    const float* __restrict__ in, const float* __restrict__ Wih,
    const float* __restrict__ bih, float* __restrict__ giseq) {
    const int ROWS = 10;  // 3200 blocks * 10 = 32000 (t,row) pairs
    int j = threadIdx.x;  // 0..191
    float wrow[64];
#pragma unroll
    for (int f4 = 0; f4 < 16; ++f4) {
        float4 w = *(const float4*)(Wih + (size_t)j * 64 + f4 * 4);
        wrow[4 * f4 + 0] = w.x; wrow[4 * f4 + 1] = w.y;
        wrow[4 * f4 + 2] = w.z; wrow[4 * f4 + 3] = w.w;
    }
    PIN64_(wrow)
    float bj = bih[j];
    int q0 = blockIdx.x * ROWS;
    int t = q0 / NROWS;            // constant per block (NROWS % ROWS == 0)
    int r0 = q0 - t * NROWS;
    for (int rr = 0; rr < ROWS; rr += 2) {
        const float *xa, *xb;
        if (MODE == 0) {
            int ra = r0 + rr, rb = ra + 1;
            int ba = ra / NN, na = ra - ba * NN;
            int bb2 = rb / NN, nb = rb - bb2 * NN;
            xa = in + (((size_t)(ba * TT + t) * NN + na) << 6);
            xb = in + (((size_t)(bb2 * TT + t) * NN + nb) << 6);
        } else {
            xa = in + ((size_t)(q0 + rr) << 6);
            xb = xa + 64;
        }
        float acca = bj, accb = bj;
#pragma unroll
        for (int f4 = 0; f4 < 16; ++f4) {
            float4 a4 = *(const float4*)(xa + f4 * 4);
            float4 b4 = *(const float4*)(xb + f4 * 4);
            acca = fmaf(a4.x, wrow[4 * f4 + 0], acca);
            acca = fmaf(a4.y, wrow[4 * f4 + 1], acca);
            acca = fmaf(a4.z, wrow[4 * f4 + 2], acca);
            acca = fmaf(a4.w, wrow[4 * f4 + 3], acca);
            accb = fmaf(b4.x, wrow[4 * f4 + 0], accb);
            accb = fmaf(b4.y, wrow[4 * f4 + 1], accb);
            accb = fmaf(b4.z, wrow[4 * f4 + 2], accb);
            accb = fmaf(b4.w, wrow[4 * f4 + 3], accb);
        }
        giseq[(size_t)(q0 + rr) * 192 + j] = acca;
        giseq[(size_t)(q0 + rr + 1) * 192 + j] = accb;
    }
}

// ---------------- GRU recurrence v3 (2 rows/wave, 1000 blocks — R7 WIN) ----------------
template <int LAYER>
__global__ __launch_bounds__(128) void gru_rec(
    const float* __restrict__ giseq, const float* __restrict__ Whh,
    const float* __restrict__ bhh, float* __restrict__ outseq) {
    __shared__ float hs[4][64];       // 2 waves * 2 rows, wave-private regions
    int tid = threadIdx.x;
    int ch = tid & 63, w = tid >> 6;  // w in {0,1}
    float wr[64], wz[64], wn[64];
#pragma unroll
    for (int k4 = 0; k4 < 16; ++k4) {
        float4 a = *(const float4*)(Whh + (size_t)ch * 64 + k4 * 4);
        float4 b = *(const float4*)(Whh + (size_t)(64 + ch) * 64 + k4 * 4);
        float4 c = *(const float4*)(Whh + (size_t)(128 + ch) * 64 + k4 * 4);
        wr[4*k4+0] = a.x; wr[4*k4+1] = a.y; wr[4*k4+2] = a.z; wr[4*k4+3] = a.w;
        wz[4*k4+0] = b.x; wz[4*k4+1] = b.y; wz[4*k4+2] = b.z; wz[4*k4+3] = b.w;
        wn[4*k4+0] = c.x; wn[4*k4+1] = c.y; wn[4*k4+2] = c.z; wn[4*k4+3] = c.w;
    }
    float br = bhh[ch], bz = bhh[64 + ch], bn = bhh[128 + ch];
    int row0 = blockIdx.x * 4 + w * 2;
    float hprev[2];
#pragma unroll
    for (int r = 0; r < 2; ++r) { hs[w * 2 + r][ch] = 0.f; hprev[r] = 0.f; }

    for (int t = 0; t < TT; ++t) {
#pragma unroll
        for (int r = 0; r < 2; ++r) {
            int row = row0 + r;
            const float* gp = giseq + ((size_t)(t * NROWS + row)) * 192;
            float gir = gp[ch], giz = gp[64 + ch], gin = gp[128 + ch];
            float ar = br, az = bz, an = bn;
#pragma unroll
            for (int k4 = 0; k4 < 16; ++k4) {
                float4 h4 = *(const float4*)&hs[w * 2 + r][k4 * 4];  // broadcast
                ar = fmaf(h4.x, wr[4*k4+0], ar); ar = fmaf(h4.y, wr[4*k4+1], ar);
                ar = fmaf(h4.z, wr[4*k4+2], ar); ar = fmaf(h4.w, wr[4*k4+3], ar);
                az = fmaf(h4.x, wz[4*k4+0], az); az = fmaf(h4.y, wz[4*k4+1], az);
                az = fmaf(h4.z, wz[4*k4+2], az); az = fmaf(h4.w, wz[4*k4+3], az);
                an = fmaf(h4.x, wn[4*k4+0], an); an = fmaf(h4.y, wn[4*k4+1], an);
                an = fmaf(h4.z, wn[4*k4+2], an); an = fmaf(h4.w, wn[4*k4+3], an);
            }
            float rg = sigmoidf_(gir + ar);
            float zg = sigmoidf_(giz + az);
            float ng = tanhf_(gin + rg * an);
            float hnew = (1.f - zg) * ng + zg * hprev[r];
            hprev[r] = hnew;
            hs[w * 2 + r][ch] = hnew;
            if (LAYER == 0)
                outseq[(((size_t)(t * NROWS + row)) << 6) + ch] = hnew;
        }
    }
    if (LAYER == 1) {
#pragma unroll
        for (int r = 0; r < 2; ++r)
            outseq[(((size_t)(row0 + r)) << 6) + ch] = hprev[r];
    }
}

// ---------------- final MLP ----------------
__global__ __launch_bounds__(64) void mlp_head(
    const float* __restrict__ hT, const float* __restrict__ pW1,
    const float* __restrict__ pb1, const float* __restrict__ pW2,
    const float* __restrict__ pb2, float* __restrict__ out) {
    int r = blockIdx.x, lane = threadIdx.x;
    __shared__ float hrow[64];
    __shared__ float mid[64];
    hrow[lane] = hT[((size_t)r << 6) + lane];
    __syncthreads();
    float acc = pb1[lane];
#pragma unroll
    for (int k = 0; k < 64; ++k) acc = fmaf(hrow[k], pW1[k * 64 + lane], acc);
    mid[lane] = fmaxf(acc, 0.f);
    __syncthreads();
    if (lane < 10) {
        float o = pb2[lane];
#pragma unroll
        for (int k = 0; k < 64; ++k) o = fmaf(mid[k], pW2[k * 10 + lane], o);
        out[(size_t)r * 10 + lane] = o;
    }
}

// ---------------- launch ----------------
extern "C" void kernel_launch(void* const* d_in, const int* in_sizes, int n_in,
                              void* d_out, int out_size, void* d_ws, size_t ws_size,
                              hipStream_t stream) {
    (void)in_sizes; (void)n_in; (void)out_size; (void)ws_size;
    const float* x    = (const float*)d_in[0];
    const int*   ei   = (const int*)d_in[1];
    const float* W1   = (const float*)d_in[3];
    const float* as1  = (const float*)d_in[4];
    const float* ad1  = (const float*)d_in[5];
    const float* b1   = (const float*)d_in[6];
    const float* W2   = (const float*)d_in[7];
    const float* as2  = (const float*)d_in[8];
    const float* ad2  = (const float*)d_in[9];
    const float* b2   = (const float*)d_in[10];
    const float* Wih0 = (const float*)d_in[13];
    const float* Whh0 = (const float*)d_in[14];
    const float* bih0 = (const float*)d_in[15];
    const float* bhh0 = (const float*)d_in[16];
    const float* Wih1 = (const float*)d_in[17];
    const float* Whh1 = (const float*)d_in[18];
    const float* bih1 = (const float*)d_in[19];
    const float* bhh1 = (const float*)d_in[20];
    const float* pW1  = (const float*)d_in[21];
    const float* pb1  = (const float*)d_in[22];
    const float* pW2  = (const float*)d_in[23];
    const float* pb2  = (const float*)d_in[24];
    float* out = (float*)d_out;

    // workspace layout (bytes); overlays noted
    char* ws = (char*)d_ws;
    ushort* hlin = (ushort*)(ws + 0);          // 16,384,000 fp16 (region 32.768MB; overlay: giseq 24.58MB)
    float* giseq = (float*)(ws + 0);
    float* asrc  = (float*)(ws + 32768000);    // 512,000     (overlay: hT)
    float* hT    = asrc;
    float* adst  = (float*)(ws + 33280000);    // 512,000
    float* gat1  = (float*)(ws + 33792000);    // 8,192,000   (overlay: h1seq)
    float* h1seq = gat1;
    float* gat2  = (float*)(ws + 41984000);    // 8,192,000
    int* counts  = (int*)(ws + 50176000);      // 128,000
    int* cursor  = (int*)(ws + 50304000);      // 128,000
    int* offs    = (int*)(ws + 50432000);      // 128,004 (padded to 128,256)
    int* csr     = (int*)(ws + 50560256);      // 2,176,000
    ushort* Bp1  = (ushort*)(ws + 52736256);   // 65,536 (region proven safe R3/R8)
    ushort* Bp2  = (ushort*)(ws + 52801792);   // 65,536 -> total 52.87MB

    hipMemsetAsync(counts, 0, 2 * GN * sizeof(int), stream);  // counts + cursor

    dim3 egrid((E2 + 255) / 256, GG);
    count_edges<<<egrid, 256, 0, stream>>>(ei, counts);
    scan_offsets_pg<<<GG, 256, 0, stream>>>(counts, offs);
    scatter_edges<<<egrid, 256, 0, stream>>>(ei, offs, cursor, csr);

    wprep<<<128, 64, 0, stream>>>(W1, W2, Bp1, Bp2);

    gat_mfma<0><<<GG * 16, 512, 0, stream>>>(x, Bp1, as1, ad1, hlin, asrc, adst);
    gat_edge<<<GN / 4, 256, 0, stream>>>(hlin, asrc, adst, offs, csr, b1, gat1, 1);
    gat_mfma<1><<<GG * 16, 512, 0, stream>>>(gat1, Bp2, as2, ad2, hlin, asrc, adst);
    gat_edge<<<GN / 4, 256, 0, stream>>>(hlin, asrc, adst, offs, csr, b2, gat2, 0);

    gru_gi<0><<<3200, 192, 0, stream>>>(gat2, Wih0, bih0, giseq);
    gru_rec<0><<<1000, 128, 0, stream>>>(giseq, Whh0, bhh0, h1seq);
    gru_gi<1><<<3200, 192, 0, stream>>>(h1seq, Wih1, bih1, giseq);
    gru_rec<1><<<1000, 128, 0, stream>>>(giseq, Whh1, bhh1, hT);

    mlp_head<<<NROWS, 64, 0, stream>>>(hT, pW1, pb1, pW2, pb2, out);
}